// Round 8
// baseline (130.605 us; speedup 1.0000x reference)
//
#include <hip/hip_runtime.h>
#include <hip/hip_bf16.h>

typedef __attribute__((ext_vector_type(8))) short short8;
typedef __attribute__((ext_vector_type(4))) float floatx4;
typedef __attribute__((ext_vector_type(4))) float f32x4;
typedef __attribute__((ext_vector_type(2))) float f32x2;
typedef unsigned short u16;
typedef unsigned int u32;
typedef __attribute__((ext_vector_type(2))) unsigned int u32x2;
typedef __attribute__((ext_vector_type(4))) unsigned int u32x4;
typedef __attribute__((ext_vector_type(8))) unsigned short ushort8;

#define LSEQ 1024
#define CHD  128
#define CEXP 0.12751744900425577f   // (1/sqrt(128)) * log2(e)
#define THR_RAW 62.73318f           // 8 / CEXP  (defer-max threshold, raw QK units)

static __device__ __forceinline__ float b2f(u16 u) {
  union { u32 i; float f; } x; x.i = ((u32)u) << 16; return x.f;
}
static __device__ __forceinline__ u32 cvtpk(float a, float b) {
  u32 r;
  asm("v_cvt_pk_bf16_f32 %0, %1, %2" : "=v"(r) : "v"(a), "v"(b));
  return r;
}
static __device__ __forceinline__ float exp2f_fast(float x) {
  float r;
  asm("v_exp_f32 %0, %1" : "=v"(r) : "v"(x));
  return r;
}
static __device__ __forceinline__ void gl_lds16(const void* g, void* l) {
  __builtin_amdgcn_global_load_lds((__attribute__((address_space(1))) const void*)g,
                                   (__attribute__((address_space(3))) void*)l, 16, 0, 0);
}

// ---- prep both inputs (z<64) + W convert (z=64,65) + stats zero ----
__global__ __launch_bounds__(256) void k_prep(const float* __restrict__ cin,
                                              const float* __restrict__ ein,
                                              const float* __restrict__ Wf,
                                              u16* __restrict__ cV, u16* __restrict__ cT,
                                              u16* __restrict__ eV, u16* __restrict__ eT,
                                              u16* __restrict__ wb, float* __restrict__ zbuf) {
  __shared__ u16 tile[32][72];
  int z = blockIdx.z;
  int tid = threadIdx.x;
  if (z >= 64) {  // W f32->bf16 + zero chsum||chsq
    int wblk = (z - 64) * 64 + blockIdx.y * 16 + blockIdx.x;
    int base = (wblk * 256 + tid) * 8;
    f32x4 a = *(const f32x4*)(Wf + base);
    f32x4 b = *(const f32x4*)(Wf + base + 4);
    u32x4 u;
    u[0] = cvtpk(a[0], a[1]); u[1] = cvtpk(a[2], a[3]);
    u[2] = cvtpk(b[0], b[1]); u[3] = cvtpk(b[2], b[3]);
    *(u32x4*)(wb + base) = u;
    if (wblk == 0) {
      f32x4 zz; zz[0]=0.f; zz[1]=0.f; zz[2]=0.f; zz[3]=0.f;
      *(f32x4*)(zbuf + tid * 4) = zz;
    }
    return;
  }
  const float* in = (z < 32) ? cin : ein;
  u16* outV = (z < 32) ? cV : eV;
  u16* outT = (z < 32) ? cT : eT;
  int bh = z & 31, c0 = blockIdx.y * 32, s0 = blockIdx.x * 64;
  int cl = tid >> 3, sc = tid & 7;
  size_t off = ((size_t)bh * CHD + c0 + cl) * LSEQ + s0 + sc * 8;
  f32x4 a = *(const f32x4*)(in + off);
  f32x4 b = *(const f32x4*)(in + off + 4);
  u32x4 u;
  u[0] = cvtpk(a[0], a[1]); u[1] = cvtpk(a[2], a[3]);
  u[2] = cvtpk(b[0], b[1]); u[3] = cvtpk(b[2], b[3]);
  *(u32x4*)(outV + off) = u;
  *(u32x4*)&tile[cl][sc * 8] = u;
  __syncthreads();
  int sl = tid >> 2, cc = tid & 3;
  ushort8 v;
#pragma unroll
  for (int j = 0; j < 8; ++j) v[j] = tile[cc * 8 + j][sl];
  *(ushort8*)(outT + ((size_t)bh * LSEQ + s0 + sl) * CHD + c0 + cc * 8) = v;
}

// ---- single flash attention, split-s partials ----
// qT,kT: bf16 [bh][1024][128]; v: bf16 [bh][128][1024].
// grid(32 bh, 16 tt, 2 sh), 256 thr (4 waves, 16 t each). LDS 36KB -> 4 blocks/CU.
// Writes UN-normalized O partial (bf16, [bh][1024t][128c] per half) + (m,l) f32 pairs.
__global__ __launch_bounds__(256, 4) void k_attn(const u16* __restrict__ qT,
                                                 const u16* __restrict__ kT,
                                                 const u16* __restrict__ v,
                                                 u16* __restrict__ O0,
                                                 u16* __restrict__ O1,
                                                 float* __restrict__ ml) {
  __shared__ char ldsbuf[36864];  // K dbuf 2x8KB | V dbuf 2x8KB | P 4x1KB

  int bh = blockIdx.x, tt = blockIdx.y, sh = blockIdx.z;
  int tid = threadIdx.x;
  int w = tid >> 6, lane = tid & 63;
  int lo = lane & 15, hi = lane >> 4;
  int t0 = tt * 64 + w * 16;

  const char* kTb = (const char*)(kT + (size_t)bh * LSEQ * CHD) + (size_t)sh * 512 * 256;
  const char* vb  = (const char*)(v  + (size_t)bh * CHD * LSEQ) + sh * 1024;  // s-offset bytes

  char* pw = ldsbuf + 32768 + w * 1024 + lo * 64;
  int swp = (lo & 3) << 4;

  auto stageK = [&](int buf, int sb) {  // 8KB: [32 s][256B c] swizzled
    char* dst = ldsbuf + buf * 8192;
#pragma unroll
    for (int it = 0; it < 2; ++it) {
      int bb = it * 4096 + tid * 16;
      int row = bb >> 8;
      int cb = (bb & 255) ^ ((row & 7) << 4);
      gl_lds16(kTb + (size_t)(sb * 32 + row) * 256 + cb, dst + bb);
    }
  };
  auto stageV = [&](int buf, int sb) {  // 8KB: [128 c][64B s] swizzled
    char* dst = ldsbuf + 16384 + buf * 8192;
#pragma unroll
    for (int it = 0; it < 2; ++it) {
      int bb = it * 4096 + tid * 16;
      int row = bb >> 6;
      int cb = (bb & 63) ^ ((row & 3) << 4);
      gl_lds16(vb + (size_t)row * 2048 + sb * 64 + cb, dst + bb);
    }
  };

  // Q B-fragments, held all kernel
  const u16* qbase = qT + ((size_t)bh * LSEQ + t0 + lo) * CHD + hi * 8;
  short8 bq[4];
#pragma unroll
  for (int ks = 0; ks < 4; ++ks) bq[ks] = *(const short8*)(qbase + ks * 32);

  floatx4 oacc[8];
#pragma unroll
  for (int i = 0; i < 8; ++i) { oacc[i][0]=0.f; oacc[i][1]=0.f; oacc[i][2]=0.f; oacc[i][3]=0.f; }
  float m_r = -1e30f, l_r = 0.f;

  stageK(0, 0); stageV(0, 0);
  for (int sb = 0; sb < 16; ++sb) {
    int cur = sb & 1;
    __builtin_amdgcn_s_barrier();                  // B1: compute(sb-1) done everywhere
    if (sb < 15) { stageK(cur ^ 1, sb + 1); stageV(cur ^ 1, sb + 1); }
    if (sb < 15) { asm volatile("s_waitcnt vmcnt(4)" ::: "memory"); }   // stage(sb) done, (sb+1) in flight
    else         { asm volatile("s_waitcnt vmcnt(0)" ::: "memory"); }
    __builtin_amdgcn_s_barrier();                  // B2: stage(sb) done everywhere

    const char* ldsK = ldsbuf + cur * 8192;
    const char* ldsV = ldsbuf + 16384 + cur * 8192;

    // S^T = K.Q (raw): lane holds S[s rows][t = t0+lo]; 8 MFMA
    float sa[2][4];
    __builtin_amdgcn_s_setprio(1);
#pragma unroll
    for (int ss = 0; ss < 2; ++ss) {
      floatx4 acc; acc[0]=0.f; acc[1]=0.f; acc[2]=0.f; acc[3]=0.f;
      int row = ss * 16 + lo;
#pragma unroll
      for (int ks = 0; ks < 4; ++ks) {
        int cbyte = (ks * 64 + hi * 16) ^ ((row & 7) << 4);
        short8 a = *(const short8*)(ldsK + row * 256 + cbyte);
        acc = __builtin_amdgcn_mfma_f32_16x16x32_bf16(a, bq[ks], acc, 0, 0, 0);
      }
#pragma unroll
      for (int r = 0; r < 4; ++r) sa[ss][r] = acc[r];
    }
    __builtin_amdgcn_s_setprio(0);

    // block max over 8 + cross-hi reduce
    float x0 = fmaxf(fmaxf(sa[0][0], sa[0][1]), sa[0][2]);
    float x1 = fmaxf(fmaxf(sa[0][3], sa[1][0]), sa[1][1]);
    float bm = fmaxf(fmaxf(x0, x1), fmaxf(sa[1][2], sa[1][3]));
    bm = fmaxf(bm, __shfl_xor(bm, 16));
    bm = fmaxf(bm, __shfl_xor(bm, 32));

    bool stay = __all(bm - m_r <= THR_RAW);
    if (!stay) {
      float mn = fmaxf(m_r, bm);
      float corr = exp2f_fast((m_r - mn) * CEXP);
      m_r = mn;
      l_r *= corr;
#pragma unroll
      for (int i = 0; i < 8; ++i) {
        oacc[i][0] *= corr; oacc[i][1] *= corr; oacc[i][2] *= corr; oacc[i][3] *= corr;
      }
    }
    float mnC = m_r * CEXP;

    float rs = 0.f;
#pragma unroll
    for (int ss = 0; ss < 2; ++ss)
#pragma unroll
      for (int r = 0; r < 4; ++r) {
        float p = exp2f_fast(__builtin_fmaf(sa[ss][r], CEXP, -mnC));
        sa[ss][r] = p;
        rs += p;
      }
    rs += __shfl_xor(rs, 16);
    rs += __shfl_xor(rs, 32);
    l_r += rs;

    // P tile (bf16) -> per-wave LDS [16 t][64B s], swizzled
#pragma unroll
    for (int ss = 0; ss < 2; ++ss) {
      u32x2 pk;
      pk[0] = cvtpk(sa[ss][0], sa[ss][1]);
      pk[1] = cvtpk(sa[ss][2], sa[ss][3]);
      *(u32x2*)(pw + ((ss * 32 + hi * 8) ^ swp)) = pk;
    }
    asm volatile("" ::: "memory");  // order P write -> P read (same-wave, TBAA hazard)

    // PV: O[c][t] += V[c][s] P[t][s]; 8 MFMA
    short8 bp = *(const short8*)(pw + ((hi * 16) ^ swp));
    __builtin_amdgcn_s_setprio(1);
#pragma unroll
    for (int mt = 0; mt < 8; ++mt) {
      int crow = mt * 16 + lo;
      short8 a = *(const short8*)(ldsV + crow * 64 + ((hi * 16) ^ ((crow & 3) << 4)));
      oacc[mt] = __builtin_amdgcn_mfma_f32_16x16x32_bf16(a, bp, oacc[mt], 0, 0, 0);
    }
    __builtin_amdgcn_s_setprio(0);
  }

  __syncthreads();  // all K/V reads done before reusing K region as transpose scratch

  // epilogue: un-normalized O -> per-wave LDS transpose tile -> coalesced partial rows
  char* ot = ldsbuf + w * 4096;  // 4 waves x 4KB = K dbuf region
#pragma unroll
  for (int mt = 0; mt < 8; ++mt) {
    u32x2 pk;
    pk[0] = cvtpk(oacc[mt][0], oacc[mt][1]);
    pk[1] = cvtpk(oacc[mt][2], oacc[mt][3]);
    *(u32x2*)(ot + lo * 256 + ((mt * 32 + hi * 8) ^ ((lo & 7) << 4))) = pk;
  }
  asm volatile("" ::: "memory");
  u16* obase = (sh ? O1 : O0) + ((size_t)bh * LSEQ + t0 + lo) * CHD;
#pragma unroll
  for (int it = 0; it < 4; ++it) {
    int cb = (it * 64 + hi * 16) ^ ((lo & 7) << 4);
    ushort8 d = *(const ushort8*)(ot + lo * 256 + cb);
    *(ushort8*)(obase + it * 32 + hi * 8) = d;
  }
  if (hi == 0) {
    f32x2 p; p[0] = m_r; p[1] = l_r;
    *(f32x2*)(ml + ((size_t)sh * 32768 + bh * LSEQ + t0 + lo) * 2) = p;
  }
}

// ---- merge two s-halves: out = (O0*e0 + O1*e1) / (l0*e0 + l1*e1), f32 math ----
__global__ __launch_bounds__(256) void k_merge(const u16* __restrict__ O0,
                                               const u16* __restrict__ O1,
                                               const float* __restrict__ ml,
                                               u16* __restrict__ outT) {
  int idx = blockIdx.x * 256 + threadIdx.x;   // 524288 total
  int tg = idx >> 4;                          // bh*1024 + t
  int cs = idx & 15;
  f32x2 ml0 = *(const f32x2*)(ml + (size_t)tg * 2);
  f32x2 ml1 = *(const f32x2*)(ml + (size_t)(32768 + tg) * 2);
  float m = fmaxf(ml0[0], ml1[0]);
  float e0 = exp2f_fast((ml0[0] - m) * CEXP);
  float e1 = exp2f_fast((ml1[0] - m) * CEXP);
  float inv = 1.0f / (ml0[1] * e0 + ml1[1] * e1);
  float s0 = e0 * inv, s1 = e1 * inv;
  size_t off = (size_t)tg * 128 + cs * 8;
  ushort8 a = *(const ushort8*)(O0 + off);
  ushort8 b = *(const ushort8*)(O1 + off);
  u32x4 o;
#pragma unroll
  for (int j = 0; j < 4; ++j) {
    float f0 = b2f(a[2 * j]) * s0 + b2f(b[2 * j]) * s1;
    float f1 = b2f(a[2 * j + 1]) * s0 + b2f(b[2 * j + 1]) * s1;
    o[j] = cvtpk(f0, f1);
  }
  *(u32x4*)(outT + off) = o;
}

// ---- proj GEMM 512(o) x 8192(b*l) x 512(c): 128x128 tile, BK=64, counted-vmcnt dbuf ----
__global__ __launch_bounds__(256) void k_proj(const u16* __restrict__ Wm,    // bf16 [512][512]
                                              const u16* __restrict__ eT,    // bf16 [32][1024][128]
                                              const float* __restrict__ bias,
                                              u16* __restrict__ x,           // bf16 [8][512][1024]
                                              float* __restrict__ chsum,
                                              float* __restrict__ chsq) {
  __shared__ char lds[65536];  // A dbuf 2x16KB | B dbuf 2x16KB
  int lt = blockIdx.x, ot = blockIdx.y;
  int b = lt >> 3;
  int l0b = (lt & 7) * 128;
  int o0 = ot * 128;
  int tid = threadIdx.x, w = tid >> 6, lane = tid & 63, lo = lane & 15, hi = lane >> 4;
  int wm = w >> 1, wn = w & 1;
  const char* Wb = (const char*)Wm;
  const char* eTb = (const char*)eT;

  auto stageA = [&](int buf, int kb) {
    char* dst = lds + buf * 16384;
#pragma unroll
    for (int it = 0; it < 4; ++it) {
      int bb = it * 4096 + tid * 16;
      int row = bb >> 7;
      int cb = (bb & 127) ^ ((row & 7) << 4);
      gl_lds16(Wb + (size_t)(o0 + row) * 1024 + kb * 128 + cb, dst + bb);
    }
  };
  auto stageB = [&](int buf, int kb) {
    char* dst = lds + 32768 + buf * 16384;
    int page = b * 4 + (kb >> 1);
    int choff = (kb & 1) * 128;
#pragma unroll
    for (int it = 0; it < 4; ++it) {
      int bb = it * 4096 + tid * 16;
      int row = bb >> 7;
      int cb = (bb & 127) ^ ((row & 7) << 4);
      gl_lds16(eTb + ((size_t)page * 1024 + l0b + row) * 256 + choff + cb, dst + bb);
    }
  };

  floatx4 acc[4][4];
#pragma unroll
  for (int i = 0; i < 4; ++i)
#pragma unroll
    for (int j = 0; j < 4; ++j) { acc[i][j][0]=0.f; acc[i][j][1]=0.f; acc[i][j][2]=0.f; acc[i][j][3]=0.f; }

  stageA(0, 0); stageB(0, 0);

  for (int kb = 0; kb < 8; ++kb) {
    int cur = kb & 1;
    __builtin_amdgcn_s_barrier();                  // B1
    if (kb < 7) { stageA(cur ^ 1, kb + 1); stageB(cur ^ 1, kb + 1); }
    if (kb < 7) { asm volatile("s_waitcnt vmcnt(8)" ::: "memory"); }
    else        { asm volatile("s_waitcnt vmcnt(0)" ::: "memory"); }
    __builtin_amdgcn_s_barrier();                  // B2
    const char* A = lds + cur * 16384;
    const char* B = lds + 32768 + cur * 16384;
#pragma unroll
    for (int kk = 0; kk < 2; ++kk) {
      short8 af[4], bf[4];
#pragma unroll
      for (int mi = 0; mi < 4; ++mi) {
        int row = wm * 64 + mi * 16 + lo;
        af[mi] = *(const short8*)(A + row * 128 + ((kk * 64 + hi * 16) ^ ((row & 7) << 4)));
      }
#pragma unroll
      for (int ni = 0; ni < 4; ++ni) {
        int row = wn * 64 + ni * 16 + lo;
        bf[ni] = *(const short8*)(B + row * 128 + ((kk * 64 + hi * 16) ^ ((row & 7) << 4)));
      }
      __builtin_amdgcn_s_setprio(1);
#pragma unroll
      for (int mi = 0; mi < 4; ++mi)
#pragma unroll
        for (int ni = 0; ni < 4; ++ni)
          acc[mi][ni] = __builtin_amdgcn_mfma_f32_16x16x32_bf16(af[mi], bf[ni], acc[mi][ni], 0, 0, 0);
      __builtin_amdgcn_s_setprio(0);
    }
  }

  // epilogue: bias + x write (bf16) + per-channel partial stats (f32)
#pragma unroll
  for (int mi = 0; mi < 4; ++mi) {
#pragma unroll
    for (int r = 0; r < 4; ++r) {
      int o = o0 + wm * 64 + mi * 16 + hi * 4 + r;
      float bv = bias[o];
      float s = 0.f, q = 0.f;
#pragma unroll
      for (int ni = 0; ni < 4; ++ni) {
        float xv = acc[mi][ni][r] + bv;
        x[((size_t)b * 512 + o) * LSEQ + l0b + wn * 64 + ni * 16 + lo] = cvtpk(xv, xv) & 0xffff;
        s += xv; q += xv * xv;
      }
#pragma unroll
      for (int d = 1; d < 16; d <<= 1) { s += __shfl_xor(s, d); q += __shfl_xor(q, d); }
      if (lo == 0) {
        atomicAdd(&chsum[o], s);
        atomicAdd(&chsq[o], q);
      }
    }
  }
}

// ---- BN apply + swish (stats folded in): bf16 x in, f32 out ----
__global__ __launch_bounds__(256) void k_final(const u16* __restrict__ x,
                                               const float* __restrict__ chsum,
                                               const float* __restrict__ chsq,
                                               const float* __restrict__ gamma,
                                               const float* __restrict__ beta,
                                               float* __restrict__ out) {
  int idx = blockIdx.x * 256 + threadIdx.x;
  int base = idx * 8;
  int ch = (base >> 10) & 511;
  const float invn = 1.0f / 8192.0f;
  float mean = chsum[ch] * invn;
  float var = chsq[ch] * invn - mean * mean;
  float rstd = rsqrtf(var + 1e-5f);
  float sc = gamma[ch] * rstd;
  float sh = beta[ch] - mean * sc;
  ushort8 vx = *(const ushort8*)(x + base);
  f32x4 o0, o1;
#pragma unroll
  for (int j = 0; j < 8; ++j) {
    float xn = b2f(vx[j]) * sc + sh;
    float sg = 1.0f / (1.0f + __expf(-xn));
    float r = xn * sg;
    if (j < 4) o0[j] = r; else o1[j - 4] = r;
  }
  *(f32x4*)(out + base) = o0;
  *(f32x4*)(out + base + 4) = o1;
}

extern "C" void kernel_launch(void* const* d_in, const int* in_sizes, int n_in,
                              void* d_out, int out_size, void* d_ws, size_t ws_size,
                              hipStream_t stream) {
  const float* c     = (const float*)d_in[0];
  const float* e     = (const float*)d_in[1];
  const float* Wf    = (const float*)d_in[2];
  const float* bias  = (const float*)d_in[3];
  const float* gamma = (const float*)d_in[4];
  const float* beta  = (const float*)d_in[5];
  float* outp = (float*)d_out;

  char* ws = (char*)d_ws;
  const size_t TB = (size_t)32 * 1024 * 128 * 2;  // 8.39MB bf16 [bh][*][*] slot
  u16* eT  = (u16*)(ws);                 // S0
  u16* cT  = (u16*)(ws + TB);            // S1 (later attn2 partial 0)
  u16* cV  = (u16*)(ws + 2 * TB);        // S2 (later attn2 partial 1)
  u16* eV  = (u16*)(ws + 3 * TB);        // S3
  u16* cT2 = (u16*)(ws + 4 * TB);        // S4: merge1 out (_cT)
  u16* xT  = (u16*)(ws + 5 * TB);        // S5: attn1 partial 0, later merge2 out (_eT)
  u16* pB  = (u16*)(ws + 6 * TB);        // S6: attn1 partial 1, later x
  u16* Wbf = (u16*)(ws + 7 * TB);        // 512KB
  float* chsum = (float*)(ws + 7 * TB + (1 << 20));
  float* chsq  = chsum + 512;
  float* ml    = (float*)(ws + 7 * TB + (1 << 20) + 8192);  // [2][32768] float2
  u16* x = pB;

  dim3 tb(256);

  k_prep<<<dim3(16, 4, 66), tb, 0, stream>>>(c, e, Wf, cV, cT, eV, eT, Wbf, chsum);
  k_attn<<<dim3(32, 16, 2), tb, 0, stream>>>(eT, cT, cV, xT, pB, ml);   // _c partials
  k_merge<<<dim3(2048), tb, 0, stream>>>(xT, pB, ml, cT2);              // _cT
  k_attn<<<dim3(32, 16, 2), tb, 0, stream>>>(cT2, eT, eV, cT, cV, ml);  // _e partials
  k_merge<<<dim3(2048), tb, 0, stream>>>(cT, cV, ml, xT);               // _eT
  k_proj<<<dim3(64, 4), tb, 0, stream>>>(Wbf, xT, bias, x, chsum, chsq);
  k_final<<<dim3(2048), tb, 0, stream>>>(x, chsum, chsq, gamma, beta, outp);
}

// Round 9
// 112.751 us; speedup vs baseline: 1.1584x; 1.1584x over previous
//
#include <hip/hip_runtime.h>
#include <hip/hip_bf16.h>

typedef __attribute__((ext_vector_type(8))) short short8;
typedef __attribute__((ext_vector_type(4))) float floatx4;
typedef __attribute__((ext_vector_type(4))) float f32x4;
typedef __attribute__((ext_vector_type(16))) float f32x16;
typedef unsigned short u16;
typedef unsigned int u32;
typedef __attribute__((ext_vector_type(2))) unsigned int u32x2;
typedef __attribute__((ext_vector_type(4))) unsigned int u32x4;
typedef __attribute__((ext_vector_type(8))) unsigned short ushort8;

#define LSEQ 1024
#define CHD  128
#define CEXP 0.12751744900425577f   // (1/sqrt(128)) * log2(e)
#define THR_RAW 62.73318f           // 8 / CEXP  (defer-max threshold, raw QK units)

static __device__ __forceinline__ float b2f(u16 u) {
  union { u32 i; float f; } x; x.i = ((u32)u) << 16; return x.f;
}
static __device__ __forceinline__ u16 f2b(float f) {
  __hip_bfloat16 h = __float2bfloat16(f);
  return *reinterpret_cast<u16*>(&h);
}
static __device__ __forceinline__ u32 cvtpk(float a, float b) {
  u32 r;
  asm("v_cvt_pk_bf16_f32 %0, %1, %2" : "=v"(r) : "v"(a), "v"(b));
  return r;
}
// v_permlane32_swap_b32: a' = {a.lo31, b.lo31}, b' = {a.hi31, b.hi31}
static __device__ __forceinline__ void swap32(u32& a, u32& b) {
  asm("v_permlane32_swap_b32 %0, %1" : "+v"(a), "+v"(b));
}
static __device__ __forceinline__ short8 mk8(u32 a, u32 b, u32 c, u32 d) {
  union { u32x4 u; short8 s; } x;
  x.u[0] = a; x.u[1] = b; x.u[2] = c; x.u[3] = d;
  return x.s;
}
static __device__ __forceinline__ float exp2f_fast(float x) {
  float r;
  asm("v_exp_f32 %0, %1" : "=v"(r) : "v"(x));
  return r;
}
static __device__ __forceinline__ void gl_lds16(const void* g, void* l) {
  __builtin_amdgcn_global_load_lds((__attribute__((address_space(1))) const void*)g,
                                   (__attribute__((address_space(3))) void*)l, 16, 0, 0);
}

// ---- prep both inputs (z<64) + W convert (z=64,65) + stats zero ----
__global__ __launch_bounds__(256) void k_prep(const float* __restrict__ cin,
                                              const float* __restrict__ ein,
                                              const float* __restrict__ Wf,
                                              u16* __restrict__ cV, u16* __restrict__ cT,
                                              u16* __restrict__ eV, u16* __restrict__ eT,
                                              u16* __restrict__ wb, float* __restrict__ zbuf) {
  __shared__ u16 tile[32][72];
  int z = blockIdx.z;
  int tid = threadIdx.x;
  if (z >= 64) {  // W f32->bf16 + zero chsum||chsq
    int wblk = (z - 64) * 64 + blockIdx.y * 16 + blockIdx.x;
    int base = (wblk * 256 + tid) * 8;
    f32x4 a = *(const f32x4*)(Wf + base);
    f32x4 b = *(const f32x4*)(Wf + base + 4);
    u32x4 u;
    u[0] = cvtpk(a[0], a[1]); u[1] = cvtpk(a[2], a[3]);
    u[2] = cvtpk(b[0], b[1]); u[3] = cvtpk(b[2], b[3]);
    *(u32x4*)(wb + base) = u;
    if (wblk == 0) {
      f32x4 zz; zz[0]=0.f; zz[1]=0.f; zz[2]=0.f; zz[3]=0.f;
      *(f32x4*)(zbuf + tid * 4) = zz;
    }
    return;
  }
  const float* in = (z < 32) ? cin : ein;
  u16* outV = (z < 32) ? cV : eV;
  u16* outT = (z < 32) ? cT : eT;
  int bh = z & 31, c0 = blockIdx.y * 32, s0 = blockIdx.x * 64;
  int cl = tid >> 3, sc = tid & 7;
  size_t off = ((size_t)bh * CHD + c0 + cl) * LSEQ + s0 + sc * 8;
  f32x4 a = *(const f32x4*)(in + off);
  f32x4 b = *(const f32x4*)(in + off + 4);
  u32x4 u;
  u[0] = cvtpk(a[0], a[1]); u[1] = cvtpk(a[2], a[3]);
  u[2] = cvtpk(b[0], b[1]); u[3] = cvtpk(b[2], b[3]);
  *(u32x4*)(outV + off) = u;
  *(u32x4*)&tile[cl][sc * 8] = u;
  __syncthreads();
  int sl = tid >> 2, cc = tid & 3;
  ushort8 v;
#pragma unroll
  for (int j = 0; j < 8; ++j) v[j] = tile[cc * 8 + j][sl];
  *(ushort8*)(outT + ((size_t)bh * LSEQ + s0 + sl) * CHD + c0 + cc * 8) = v;
}

// ---- fused double flash attention, 32x32x16 MFMA, in-register P & handoff ----
// eT,cT: bf16 [bh][1024][128]; cV,eV: bf16 [bh][128][1024]; outT: bf16 [bh][1024][128].
// grid(16 tt, 32 bh), 128 thr (2 waves, t=32 each). LDS 64KB -> 2 blocks/CU.
__global__ __launch_bounds__(128) void k_attn(const u16* __restrict__ eT,
                                              const u16* __restrict__ cT,
                                              const u16* __restrict__ cV,
                                              const u16* __restrict__ eV,
                                              u16* __restrict__ outT) {
  __shared__ char ldsbuf[65536];  // K dbuf 2x16KB | V dbuf 2x16KB

  int tt = blockIdx.x, bh = blockIdx.y;
  int tid = threadIdx.x;
  int w = tid >> 6, lane = tid & 63;
  int ln = lane & 31, h = lane >> 5;
  int t0 = tt * 64 + w * 32;

  auto stageK = [&](int buf, int sb, const char* kTb) {  // [64 s][256B c], row&15 swz
    char* dst = ldsbuf + buf * 16384;
#pragma unroll
    for (int it = 0; it < 8; ++it) {
      int bb = it * 2048 + tid * 16;
      int row = bb >> 8;
      int cb = (bb & 255) ^ ((row & 15) << 4);
      gl_lds16(kTb + (size_t)(sb * 64 + row) * 256 + cb, dst + bb);
    }
  };
  auto stageV = [&](int buf, int sb, const char* vb) {   // [128 c][128B s], row&7 swz
    char* dst = ldsbuf + 32768 + buf * 16384;
#pragma unroll
    for (int it = 0; it < 8; ++it) {
      int bb = it * 2048 + tid * 16;
      int row = bb >> 7;
      int cb = (bb & 127) ^ ((row & 7) << 4);
      gl_lds16(vb + (size_t)row * 2048 + sb * 128 + cb, dst + bb);
    }
  };

  short8 bq[8];      // Q B-frags (phase1: global; phase2: in-reg handoff)
  f32x16 oacc[4];    // O[c=128][t=32]: col=t=ln, row c=32m+(r&3)+8(r>>2)+4h
  float m_r, l_r;

  auto flash = [&](const char* kTb, const char* vb) {
    m_r = -1e30f; l_r = 0.f;
#pragma unroll
    for (int i = 0; i < 4; ++i)
#pragma unroll
      for (int r = 0; r < 16; ++r) oacc[i][r] = 0.f;

    stageK(0, 0, kTb); stageV(0, 0, vb);
    for (int sb = 0; sb < 16; ++sb) {
      int cur = sb & 1;
      __builtin_amdgcn_s_barrier();   // B1: compute(sb-1) done everywhere
      if (sb < 15) { stageK(cur ^ 1, sb + 1, kTb); stageV(cur ^ 1, sb + 1, vb); }
      if (sb < 15) { asm volatile("s_waitcnt vmcnt(16)" ::: "memory"); }
      else         { asm volatile("s_waitcnt vmcnt(0)" ::: "memory"); }
      __builtin_amdgcn_s_barrier();   // B2: stage(sb) visible everywhere

      const char* ldsK = ldsbuf + cur * 16384;
      const char* ldsV = ldsbuf + 32768 + cur * 16384;

      // S^T[64 s][32 t] = K.Q ; lane col = t0+ln
      f32x16 sa0, sa1;
#pragma unroll
      for (int r = 0; r < 16; ++r) { sa0[r] = 0.f; sa1[r] = 0.f; }
      __builtin_amdgcn_s_setprio(1);
#pragma unroll
      for (int k = 0; k < 8; ++k) {
        int col = k * 32 + (h << 4);
        int r0 = ln, r1 = 32 + ln;
        short8 a0 = *(const short8*)(ldsK + r0 * 256 + (col ^ ((r0 & 15) << 4)));
        short8 a1 = *(const short8*)(ldsK + r1 * 256 + (col ^ ((r1 & 15) << 4)));
        sa0 = __builtin_amdgcn_mfma_f32_32x32x16_bf16(a0, bq[k], sa0, 0, 0, 0);
        sa1 = __builtin_amdgcn_mfma_f32_32x32x16_bf16(a1, bq[k], sa1, 0, 0, 0);
      }
      __builtin_amdgcn_s_setprio(0);

      // online softmax over s for this t (in-lane 32 + xor32)
      float bm = sa0[0];
#pragma unroll
      for (int r = 1; r < 16; ++r) bm = fmaxf(bm, sa0[r]);
#pragma unroll
      for (int r = 0; r < 16; ++r) bm = fmaxf(bm, sa1[r]);
      bm = fmaxf(bm, __shfl_xor(bm, 32));

      bool stay = __all(bm - m_r <= THR_RAW);
      if (!stay) {
        float mn = fmaxf(m_r, bm);
        float corr = exp2f_fast((m_r - mn) * CEXP);
        m_r = mn; l_r *= corr;
#pragma unroll
        for (int i = 0; i < 4; ++i)
#pragma unroll
          for (int r = 0; r < 16; ++r) oacc[i][r] *= corr;
      }
      float mnC = m_r * CEXP;

      float rs = 0.f;
#pragma unroll
      for (int r = 0; r < 16; ++r) {
        float p = exp2f_fast(__builtin_fmaf(sa0[r], CEXP, -mnC));
        sa0[r] = p; rs += p;
      }
#pragma unroll
      for (int r = 0; r < 16; ++r) {
        float p = exp2f_fast(__builtin_fmaf(sa1[r], CEXP, -mnC));
        sa1[r] = p; rs += p;
      }
      rs += __shfl_xor(rs, 32);
      l_r += rs;

      // P -> PV B-frags entirely in registers (cvt_pk + permlane32_swap)
      short8 bp[4];
      {
        u32 w0 = cvtpk(sa0[0], sa0[1]),  w1 = cvtpk(sa0[2], sa0[3]);
        u32 w2 = cvtpk(sa0[4], sa0[5]),  w3 = cvtpk(sa0[6], sa0[7]);
        swap32(w0, w2); swap32(w1, w3);
        bp[0] = mk8(w0, w1, w2, w3);
        u32 w4 = cvtpk(sa0[8], sa0[9]),  w5 = cvtpk(sa0[10], sa0[11]);
        u32 w6 = cvtpk(sa0[12], sa0[13]), w7 = cvtpk(sa0[14], sa0[15]);
        swap32(w4, w6); swap32(w5, w7);
        bp[1] = mk8(w4, w5, w6, w7);
        u32 x0 = cvtpk(sa1[0], sa1[1]),  x1 = cvtpk(sa1[2], sa1[3]);
        u32 x2 = cvtpk(sa1[4], sa1[5]),  x3 = cvtpk(sa1[6], sa1[7]);
        swap32(x0, x2); swap32(x1, x3);
        bp[2] = mk8(x0, x1, x2, x3);
        u32 x4 = cvtpk(sa1[8], sa1[9]),  x5 = cvtpk(sa1[10], sa1[11]);
        u32 x6 = cvtpk(sa1[12], sa1[13]), x7 = cvtpk(sa1[14], sa1[15]);
        swap32(x4, x6); swap32(x5, x7);
        bp[3] = mk8(x4, x5, x6, x7);
      }

      // PV: O[c][t] += V[c][s] P^T[s][t]
      __builtin_amdgcn_s_setprio(1);
#pragma unroll
      for (int ks = 0; ks < 4; ++ks) {
        int col = ks * 32 + (h << 4);
#pragma unroll
        for (int m = 0; m < 4; ++m) {
          int row = m * 32 + ln;
          short8 a = *(const short8*)(ldsV + row * 128 + (col ^ ((row & 7) << 4)));
          oacc[m] = __builtin_amdgcn_mfma_f32_32x32x16_bf16(a, bp[ks], oacc[m], 0, 0, 0);
        }
      }
      __builtin_amdgcn_s_setprio(0);
      // no trailing barrier; next iteration's B1 covers it
    }
  };

  // ---------------- phase 1: _c tile = attn(e, c, c) ----------------
  const u16* qbase = eT + ((size_t)bh * LSEQ + t0 + ln) * CHD + h * 8;
#pragma unroll
  for (int k = 0; k < 8; ++k) bq[k] = *(const short8*)(qbase + k * 16);

  flash((const char*)(cT + (size_t)bh * LSEQ * CHD),
        (const char*)(cV + (size_t)bh * CHD * LSEQ));

  // handoff: O1 (normalized) -> phase-2 Q B-frags, in-register
  {
    float inv = 1.0f / l_r;
#pragma unroll
    for (int m = 0; m < 4; ++m) {
      u32 w0 = cvtpk(oacc[m][0]*inv,  oacc[m][1]*inv),  w1 = cvtpk(oacc[m][2]*inv,  oacc[m][3]*inv);
      u32 w2 = cvtpk(oacc[m][4]*inv,  oacc[m][5]*inv),  w3 = cvtpk(oacc[m][6]*inv,  oacc[m][7]*inv);
      swap32(w0, w2); swap32(w1, w3);
      bq[2*m] = mk8(w0, w1, w2, w3);
      u32 w4 = cvtpk(oacc[m][8]*inv,  oacc[m][9]*inv),  w5 = cvtpk(oacc[m][10]*inv, oacc[m][11]*inv);
      u32 w6 = cvtpk(oacc[m][12]*inv, oacc[m][13]*inv), w7 = cvtpk(oacc[m][14]*inv, oacc[m][15]*inv);
      swap32(w4, w6); swap32(w5, w7);
      bq[2*m+1] = mk8(w4, w5, w6, w7);
    }
  }

  // ---------------- phase 2: _e tile = attn(_c, e, e) ----------------
  flash((const char*)(eT + (size_t)bh * LSEQ * CHD),
        (const char*)(eV + (size_t)bh * CHD * LSEQ));

  // epilogue: O2 -> per-wave LDS transpose tile (8KB in K buf0) -> coalesced outT rows
  {
    float inv = 1.0f / l_r;
    char* ot = ldsbuf + w * 8192;  // [32 t][256B c]; last compute used buf1 -> safe
#pragma unroll
    for (int m = 0; m < 4; ++m)
#pragma unroll
      for (int q = 0; q < 8; ++q) {
        u32 pk = cvtpk(oacc[m][2*q] * inv, oacc[m][2*q+1] * inv);
        int c2 = m * 64 + 4 * (q & 1) + 16 * (q >> 1) + 8 * h;  // byte col
        *(u32*)(ot + ln * 256 + (c2 ^ ((ln & 7) << 4))) = pk;
      }
    asm volatile("" ::: "memory");  // same-wave write->read ordering
    u16* orow = outT + ((size_t)bh * LSEQ + t0 + ln) * CHD;
#pragma unroll
    for (int it = 0; it < 8; ++it) {
      int col = h * 128 + it * 16;
      ushort8 d = *(const ushort8*)(ot + ln * 256 + (col ^ ((ln & 7) << 4)));
      *(ushort8*)((char*)orow + col) = d;
    }
  }
}

// ---- proj GEMM 512(o) x 8192(b*l) x 512(c): 128x128 tile, BK=64, counted-vmcnt dbuf ----
__global__ __launch_bounds__(256) void k_proj(const u16* __restrict__ Wm,    // bf16 [512][512]
                                              const u16* __restrict__ eT,    // bf16 [32][1024][128]
                                              const float* __restrict__ bias,
                                              u16* __restrict__ x,           // bf16 [8][512][1024]
                                              float* __restrict__ chsum,
                                              float* __restrict__ chsq) {
  __shared__ char lds[65536];  // A dbuf 2x16KB | B dbuf 2x16KB
  int lt = blockIdx.x, ot = blockIdx.y;
  int b = lt >> 3;
  int l0b = (lt & 7) * 128;
  int o0 = ot * 128;
  int tid = threadIdx.x, w = tid >> 6, lane = tid & 63, lo = lane & 15, hi = lane >> 4;
  int wm = w >> 1, wn = w & 1;
  const char* Wb = (const char*)Wm;
  const char* eTb = (const char*)eT;

  auto stageA = [&](int buf, int kb) {
    char* dst = lds + buf * 16384;
#pragma unroll
    for (int it = 0; it < 4; ++it) {
      int bb = it * 4096 + tid * 16;
      int row = bb >> 7;
      int cb = (bb & 127) ^ ((row & 7) << 4);
      gl_lds16(Wb + (size_t)(o0 + row) * 1024 + kb * 128 + cb, dst + bb);
    }
  };
  auto stageB = [&](int buf, int kb) {
    char* dst = lds + 32768 + buf * 16384;
    int page = b * 4 + (kb >> 1);
    int choff = (kb & 1) * 128;
#pragma unroll
    for (int it = 0; it < 4; ++it) {
      int bb = it * 4096 + tid * 16;
      int row = bb >> 7;
      int cb = (bb & 127) ^ ((row & 7) << 4);
      gl_lds16(eTb + ((size_t)page * 1024 + l0b + row) * 256 + choff + cb, dst + bb);
    }
  };

  floatx4 acc[4][4];
#pragma unroll
  for (int i = 0; i < 4; ++i)
#pragma unroll
    for (int j = 0; j < 4; ++j) { acc[i][j][0]=0.f; acc[i][j][1]=0.f; acc[i][j][2]=0.f; acc[i][j][3]=0.f; }

  stageA(0, 0); stageB(0, 0);

  for (int kb = 0; kb < 8; ++kb) {
    int cur = kb & 1;
    __builtin_amdgcn_s_barrier();                  // B1
    if (kb < 7) { stageA(cur ^ 1, kb + 1); stageB(cur ^ 1, kb + 1); }
    if (kb < 7) { asm volatile("s_waitcnt vmcnt(8)" ::: "memory"); }
    else        { asm volatile("s_waitcnt vmcnt(0)" ::: "memory"); }
    __builtin_amdgcn_s_barrier();                  // B2
    const char* A = lds + cur * 16384;
    const char* B = lds + 32768 + cur * 16384;
#pragma unroll
    for (int kk = 0; kk < 2; ++kk) {
      short8 af[4], bf[4];
#pragma unroll
      for (int mi = 0; mi < 4; ++mi) {
        int row = wm * 64 + mi * 16 + lo;
        af[mi] = *(const short8*)(A + row * 128 + ((kk * 64 + hi * 16) ^ ((row & 7) << 4)));
      }
#pragma unroll
      for (int ni = 0; ni < 4; ++ni) {
        int row = wn * 64 + ni * 16 + lo;
        bf[ni] = *(const short8*)(B + row * 128 + ((kk * 64 + hi * 16) ^ ((row & 7) << 4)));
      }
      __builtin_amdgcn_s_setprio(1);
#pragma unroll
      for (int mi = 0; mi < 4; ++mi)
#pragma unroll
        for (int ni = 0; ni < 4; ++ni)
          acc[mi][ni] = __builtin_amdgcn_mfma_f32_16x16x32_bf16(af[mi], bf[ni], acc[mi][ni], 0, 0, 0);
      __builtin_amdgcn_s_setprio(0);
    }
  }

  // epilogue: bias + x write (bf16) + per-channel partial stats (f32)
#pragma unroll
  for (int mi = 0; mi < 4; ++mi) {
#pragma unroll
    for (int r = 0; r < 4; ++r) {
      int o = o0 + wm * 64 + mi * 16 + hi * 4 + r;
      float bv = bias[o];
      float s = 0.f, q = 0.f;
#pragma unroll
      for (int ni = 0; ni < 4; ++ni) {
        float xv = acc[mi][ni][r] + bv;
        x[((size_t)b * 512 + o) * LSEQ + l0b + wn * 64 + ni * 16 + lo] = f2b(xv);
        s += xv; q += xv * xv;
      }
#pragma unroll
      for (int d = 1; d < 16; d <<= 1) { s += __shfl_xor(s, d); q += __shfl_xor(q, d); }
      if (lo == 0) {
        atomicAdd(&chsum[o], s);
        atomicAdd(&chsq[o], q);
      }
    }
  }
}

// ---- BN apply + swish (stats folded in): bf16 x in, f32 out ----
__global__ __launch_bounds__(256) void k_final(const u16* __restrict__ x,
                                               const float* __restrict__ chsum,
                                               const float* __restrict__ chsq,
                                               const float* __restrict__ gamma,
                                               const float* __restrict__ beta,
                                               float* __restrict__ out) {
  int idx = blockIdx.x * 256 + threadIdx.x;
  int base = idx * 8;
  int ch = (base >> 10) & 511;
  const float invn = 1.0f / 8192.0f;
  float mean = chsum[ch] * invn;
  float var = chsq[ch] * invn - mean * mean;
  float rstd = rsqrtf(var + 1e-5f);
  float sc = gamma[ch] * rstd;
  float sh = beta[ch] - mean * sc;
  ushort8 vx = *(const ushort8*)(x + base);
  f32x4 o0, o1;
#pragma unroll
  for (int j = 0; j < 8; ++j) {
    float xn = b2f(vx[j]) * sc + sh;
    float sg = 1.0f / (1.0f + __expf(-xn));
    float r = xn * sg;
    if (j < 4) o0[j] = r; else o1[j - 4] = r;
  }
  *(f32x4*)(out + base) = o0;
  *(f32x4*)(out + base + 4) = o1;
}

extern "C" void kernel_launch(void* const* d_in, const int* in_sizes, int n_in,
                              void* d_out, int out_size, void* d_ws, size_t ws_size,
                              hipStream_t stream) {
  const float* c     = (const float*)d_in[0];
  const float* e     = (const float*)d_in[1];
  const float* Wf    = (const float*)d_in[2];
  const float* bias  = (const float*)d_in[3];
  const float* gamma = (const float*)d_in[4];
  const float* beta  = (const float*)d_in[5];
  float* outp = (float*)d_out;

  char* ws = (char*)d_ws;
  const size_t TB = (size_t)32 * 1024 * 128 * 2;  // 8.39MB bf16 [bh][*][*] slot
  u16* eT  = (u16*)(ws);                 // S0
  u16* cT  = (u16*)(ws + TB);            // S1
  u16* cV  = (u16*)(ws + 2 * TB);        // S2
  u16* eV  = (u16*)(ws + 3 * TB);        // S3
  u16* xT  = (u16*)(ws + 4 * TB);        // S4: _eT (fused attn output)
  u16* Wbf = (u16*)(ws + 5 * TB);        // 512KB
  float* chsum = (float*)(ws + 5 * TB + (1 << 20));
  float* chsq  = chsum + 512;
  u16* x   = (u16*)(ws + 6 * TB);        // bf16 8.4MB

  dim3 tb(256);

  k_prep<<<dim3(16, 4, 66), tb, 0, stream>>>(c, e, Wf, cV, cT, eV, eT, Wbf, chsum);
  k_attn<<<dim3(16, 32), dim3(128), 0, stream>>>(eT, cT, cV, eV, xT);  // _eT fused
  k_proj<<<dim3(64, 4), tb, 0, stream>>>(Wbf, xT, bias, x, chsum, chsq);
  k_final<<<dim3(2048), tb, 0, stream>>>(x, chsum, chsq, gamma, beta, outp);
}

// Round 10
// 112.430 us; speedup vs baseline: 1.1617x; 1.0029x over previous
//
#include <hip/hip_runtime.h>
#include <hip/hip_bf16.h>

typedef __attribute__((ext_vector_type(8))) short short8;
typedef __attribute__((ext_vector_type(4))) float floatx4;
typedef __attribute__((ext_vector_type(4))) float f32x4;
typedef __attribute__((ext_vector_type(16))) float f32x16;
typedef unsigned short u16;
typedef unsigned int u32;
typedef __attribute__((ext_vector_type(2))) unsigned int u32x2;
typedef __attribute__((ext_vector_type(4))) unsigned int u32x4;
typedef __attribute__((ext_vector_type(8))) unsigned short ushort8;

#define LSEQ 1024
#define CHD  128
#define CEXP 0.12751744900425577f   // (1/sqrt(128)) * log2(e)
#define THR_RAW 62.73318f           // 8 / CEXP  (defer-max threshold, raw QK units)

static __device__ __forceinline__ float b2f(u16 u) {
  union { u32 i; float f; } x; x.i = ((u32)u) << 16; return x.f;
}
static __device__ __forceinline__ u16 f2b(float f) {
  __hip_bfloat16 h = __float2bfloat16(f);
  return *reinterpret_cast<u16*>(&h);
}
static __device__ __forceinline__ u32 cvtpk(float a, float b) {
  u32 r;
  asm("v_cvt_pk_bf16_f32 %0, %1, %2" : "=v"(r) : "v"(a), "v"(b));
  return r;
}
// v_permlane32_swap_b32: a' = {a.lo31, b.lo31}, b' = {a.hi31, b.hi31}
static __device__ __forceinline__ void swap32(u32& a, u32& b) {
  asm("v_permlane32_swap_b32 %0, %1" : "+v"(a), "+v"(b));
}
static __device__ __forceinline__ short8 mk8(u32 a, u32 b, u32 c, u32 d) {
  union { u32x4 u; short8 s; } x;
  x.u[0] = a; x.u[1] = b; x.u[2] = c; x.u[3] = d;
  return x.s;
}
static __device__ __forceinline__ float exp2f_fast(float x) {
  float r;
  asm("v_exp_f32 %0, %1" : "=v"(r) : "v"(x));
  return r;
}
static __device__ __forceinline__ void gl_lds16(const void* g, void* l) {
  __builtin_amdgcn_global_load_lds((__attribute__((address_space(1))) const void*)g,
                                   (__attribute__((address_space(3))) void*)l, 16, 0, 0);
}

// ---- prep both inputs (z<64) + W convert (z=64,65) + stats zero ----
__global__ __launch_bounds__(256) void k_prep(const float* __restrict__ cin,
                                              const float* __restrict__ ein,
                                              const float* __restrict__ Wf,
                                              u16* __restrict__ cV, u16* __restrict__ cT,
                                              u16* __restrict__ eV, u16* __restrict__ eT,
                                              u16* __restrict__ wb, float* __restrict__ zbuf) {
  __shared__ u16 tile[32][72];
  int z = blockIdx.z;
  int tid = threadIdx.x;
  if (z >= 64) {  // W f32->bf16 + zero chsum||chsq
    int wblk = (z - 64) * 64 + blockIdx.y * 16 + blockIdx.x;
    int base = (wblk * 256 + tid) * 8;
    f32x4 a = *(const f32x4*)(Wf + base);
    f32x4 b = *(const f32x4*)(Wf + base + 4);
    u32x4 u;
    u[0] = cvtpk(a[0], a[1]); u[1] = cvtpk(a[2], a[3]);
    u[2] = cvtpk(b[0], b[1]); u[3] = cvtpk(b[2], b[3]);
    *(u32x4*)(wb + base) = u;
    if (wblk == 0) {
      f32x4 zz; zz[0]=0.f; zz[1]=0.f; zz[2]=0.f; zz[3]=0.f;
      *(f32x4*)(zbuf + tid * 4) = zz;
    }
    return;
  }
  const float* in = (z < 32) ? cin : ein;
  u16* outV = (z < 32) ? cV : eV;
  u16* outT = (z < 32) ? cT : eT;
  int bh = z & 31, c0 = blockIdx.y * 32, s0 = blockIdx.x * 64;
  int cl = tid >> 3, sc = tid & 7;
  size_t off = ((size_t)bh * CHD + c0 + cl) * LSEQ + s0 + sc * 8;
  f32x4 a = *(const f32x4*)(in + off);
  f32x4 b = *(const f32x4*)(in + off + 4);
  u32x4 u;
  u[0] = cvtpk(a[0], a[1]); u[1] = cvtpk(a[2], a[3]);
  u[2] = cvtpk(b[0], b[1]); u[3] = cvtpk(b[2], b[3]);
  *(u32x4*)(outV + off) = u;
  *(u32x4*)&tile[cl][sc * 8] = u;
  __syncthreads();
  int sl = tid >> 2, cc = tid & 3;
  ushort8 v;
#pragma unroll
  for (int j = 0; j < 8; ++j) v[j] = tile[cc * 8 + j][sl];
  *(ushort8*)(outT + ((size_t)bh * LSEQ + s0 + sl) * CHD + c0 + cc * 8) = v;
}

// ---- fused double flash attention, 32x32x16, deferred-PV pipeline ----
// grid(32 bh, 16 tt), 128 thr (2 waves, t=32 each). LDS 80KB -> 2 blocks/CU.
// K dbuf 2x16KB | V tbuf 3x16KB (triple: PV(sb-1) overlaps stage(sb+1)).
__global__ __launch_bounds__(128) void k_attn(const u16* __restrict__ eT,
                                              const u16* __restrict__ cT,
                                              const u16* __restrict__ cV,
                                              const u16* __restrict__ eV,
                                              u16* __restrict__ outT) {
  __shared__ char ldsbuf[81920];

  int bh = blockIdx.x, tt = blockIdx.y;
  int tid = threadIdx.x;
  int w = tid >> 6, lane = tid & 63;
  int ln = lane & 31, h = lane >> 5;
  int t0 = tt * 64 + w * 32;

  auto stageK = [&](int buf, int sb, const char* kTb) {  // [64 s][256B c], row&15 swz
    char* dst = ldsbuf + buf * 16384;
#pragma unroll
    for (int it = 0; it < 8; ++it) {
      int bb = it * 2048 + tid * 16;
      int row = bb >> 8;
      int cb = (bb & 255) ^ ((row & 15) << 4);
      gl_lds16(kTb + (size_t)(sb * 64 + row) * 256 + cb, dst + bb);
    }
  };
  auto stageV = [&](int buf, int sb, const char* vb) {   // [128 c][128B s], row&7 swz
    char* dst = ldsbuf + 32768 + buf * 16384;
#pragma unroll
    for (int it = 0; it < 8; ++it) {
      int bb = it * 2048 + tid * 16;
      int row = bb >> 7;
      int cb = (bb & 127) ^ ((row & 7) << 4);
      gl_lds16(vb + (size_t)row * 2048 + sb * 128 + cb, dst + bb);
    }
  };

  short8 bq[8];      // Q B-frags (phase1: global; phase2: in-reg handoff)
  f32x16 oacc[4];    // O[c=128][t=32]: col=t=ln, row c=32m+(r&3)+8(r>>2)+4h
  float m_r, l_r;

  auto flash = [&](const char* kTb, const char* vb) {
    m_r = -1e30f; l_r = 0.f;
#pragma unroll
    for (int i = 0; i < 4; ++i)
#pragma unroll
      for (int r = 0; r < 16; ++r) oacc[i][r] = 0.f;

    short8 bp[4];    // P fragments of the PREVIOUS s-block (deferred PV)
    stageK(0, 0, kTb); stageV(0, 0, vb);
    for (int sb = 0; sb < 16; ++sb) {
      __builtin_amdgcn_s_barrier();   // B1: all waves done with buffers being re-staged
      if (sb < 15) { stageK((sb + 1) & 1, sb + 1, kTb); stageV((sb + 1) % 3, sb + 1, vb); }
      if (sb < 15) { asm volatile("s_waitcnt vmcnt(16)" ::: "memory"); }
      else         { asm volatile("s_waitcnt vmcnt(0)" ::: "memory"); }
      __builtin_amdgcn_s_barrier();   // B2: stage(sb) visible everywhere

      const char* ldsK = ldsbuf + (sb & 1) * 16384;

      // QK: S^T[64 s][32 t]; lane col = t0+ln
      f32x16 sa0, sa1;
#pragma unroll
      for (int r = 0; r < 16; ++r) { sa0[r] = 0.f; sa1[r] = 0.f; }
      __builtin_amdgcn_s_setprio(1);
#pragma unroll
      for (int k = 0; k < 8; ++k) {
        int col = k * 32 + (h << 4);
        int r0 = ln, r1 = 32 + ln;
        short8 a0 = *(const short8*)(ldsK + r0 * 256 + (col ^ ((r0 & 15) << 4)));
        short8 a1 = *(const short8*)(ldsK + r1 * 256 + (col ^ ((r1 & 15) << 4)));
        sa0 = __builtin_amdgcn_mfma_f32_32x32x16_bf16(a0, bq[k], sa0, 0, 0, 0);
        sa1 = __builtin_amdgcn_mfma_f32_32x32x16_bf16(a1, bq[k], sa1, 0, 0, 0);
      }

      // deferred PV(sb-1): independent of sa -> overlaps with softmax below
      if (sb > 0) {
        const char* ldsVp = ldsbuf + 32768 + ((sb - 1) % 3) * 16384;
#pragma unroll
        for (int ks = 0; ks < 4; ++ks) {
          int col = ks * 32 + (h << 4);
#pragma unroll
          for (int m = 0; m < 4; ++m) {
            int row = m * 32 + ln;
            short8 a = *(const short8*)(ldsVp + row * 128 + (col ^ ((row & 7) << 4)));
            oacc[m] = __builtin_amdgcn_mfma_f32_32x32x16_bf16(a, bp[ks], oacc[m], 0, 0, 0);
          }
        }
      }
      __builtin_amdgcn_s_setprio(0);

      // softmax(sb) on VALU — overlaps PV MFMA drain
      float bm = sa0[0];
#pragma unroll
      for (int r = 1; r < 16; ++r) bm = fmaxf(bm, sa0[r]);
#pragma unroll
      for (int r = 0; r < 16; ++r) bm = fmaxf(bm, sa1[r]);
      bm = fmaxf(bm, __shfl_xor(bm, 32));

      bool stay = __all(bm - m_r <= THR_RAW);
      if (!stay) {
        float mn = fmaxf(m_r, bm);
        float corr = exp2f_fast((m_r - mn) * CEXP);
        m_r = mn; l_r *= corr;
        // note: oacc rescale reads PV(sb-1) results -> register deps keep order
#pragma unroll
        for (int i = 0; i < 4; ++i)
#pragma unroll
          for (int r = 0; r < 16; ++r) oacc[i][r] *= corr;
      }
      float mnC = m_r * CEXP;

      float rs = 0.f;
#pragma unroll
      for (int r = 0; r < 16; ++r) {
        float p = exp2f_fast(__builtin_fmaf(sa0[r], CEXP, -mnC));
        sa0[r] = p; rs += p;
      }
#pragma unroll
      for (int r = 0; r < 16; ++r) {
        float p = exp2f_fast(__builtin_fmaf(sa1[r], CEXP, -mnC));
        sa1[r] = p; rs += p;
      }
      rs += __shfl_xor(rs, 32);
      l_r += rs;

      // build bp(sb) in registers (cvt_pk + permlane32_swap)
      {
        u32 w0 = cvtpk(sa0[0], sa0[1]),  w1 = cvtpk(sa0[2], sa0[3]);
        u32 w2 = cvtpk(sa0[4], sa0[5]),  w3 = cvtpk(sa0[6], sa0[7]);
        swap32(w0, w2); swap32(w1, w3);
        bp[0] = mk8(w0, w1, w2, w3);
        u32 w4 = cvtpk(sa0[8], sa0[9]),  w5 = cvtpk(sa0[10], sa0[11]);
        u32 w6 = cvtpk(sa0[12], sa0[13]), w7 = cvtpk(sa0[14], sa0[15]);
        swap32(w4, w6); swap32(w5, w7);
        bp[1] = mk8(w4, w5, w6, w7);
        u32 x0 = cvtpk(sa1[0], sa1[1]),  x1 = cvtpk(sa1[2], sa1[3]);
        u32 x2 = cvtpk(sa1[4], sa1[5]),  x3 = cvtpk(sa1[6], sa1[7]);
        swap32(x0, x2); swap32(x1, x3);
        bp[2] = mk8(x0, x1, x2, x3);
        u32 x4 = cvtpk(sa1[8], sa1[9]),  x5 = cvtpk(sa1[10], sa1[11]);
        u32 x6 = cvtpk(sa1[12], sa1[13]), x7 = cvtpk(sa1[14], sa1[15]);
        swap32(x4, x6); swap32(x5, x7);
        bp[3] = mk8(x4, x5, x6, x7);
      }
    }

    // tail PV(15): V(15) lives in buf 15%3=0, never overwritten after
    {
      const char* ldsVp = ldsbuf + 32768 + (15 % 3) * 16384;
      __builtin_amdgcn_s_setprio(1);
#pragma unroll
      for (int ks = 0; ks < 4; ++ks) {
        int col = ks * 32 + (h << 4);
#pragma unroll
        for (int m = 0; m < 4; ++m) {
          int row = m * 32 + ln;
          short8 a = *(const short8*)(ldsVp + row * 128 + (col ^ ((row & 7) << 4)));
          oacc[m] = __builtin_amdgcn_mfma_f32_32x32x16_bf16(a, bp[ks], oacc[m], 0, 0, 0);
        }
      }
      __builtin_amdgcn_s_setprio(0);
    }
  };

  // ---------------- phase 1: _c tile = attn(e, c, c) ----------------
  const u16* qbase = eT + ((size_t)bh * LSEQ + t0 + ln) * CHD + h * 8;
#pragma unroll
  for (int k = 0; k < 8; ++k) bq[k] = *(const short8*)(qbase + k * 16);

  flash((const char*)(cT + (size_t)bh * LSEQ * CHD),
        (const char*)(cV + (size_t)bh * CHD * LSEQ));

  // handoff: O1 (normalized) -> phase-2 Q B-frags, in-register
  {
    float inv = 1.0f / l_r;
#pragma unroll
    for (int m = 0; m < 4; ++m) {
      u32 w0 = cvtpk(oacc[m][0]*inv,  oacc[m][1]*inv),  w1 = cvtpk(oacc[m][2]*inv,  oacc[m][3]*inv);
      u32 w2 = cvtpk(oacc[m][4]*inv,  oacc[m][5]*inv),  w3 = cvtpk(oacc[m][6]*inv,  oacc[m][7]*inv);
      swap32(w0, w2); swap32(w1, w3);
      bq[2*m] = mk8(w0, w1, w2, w3);
      u32 w4 = cvtpk(oacc[m][8]*inv,  oacc[m][9]*inv),  w5 = cvtpk(oacc[m][10]*inv, oacc[m][11]*inv);
      u32 w6 = cvtpk(oacc[m][12]*inv, oacc[m][13]*inv), w7 = cvtpk(oacc[m][14]*inv, oacc[m][15]*inv);
      swap32(w4, w6); swap32(w5, w7);
      bq[2*m+1] = mk8(w4, w5, w6, w7);
    }
  }
  __syncthreads();  // phase-1 LDS reads fully done before phase-2 staging

  // ---------------- phase 2: _e tile = attn(_c, e, e) ----------------
  flash((const char*)(eT + (size_t)bh * LSEQ * CHD),
        (const char*)(eV + (size_t)bh * CHD * LSEQ));

  // epilogue: O2 -> per-wave LDS transpose tile (K buf region) -> coalesced outT rows
  {
    float inv = 1.0f / l_r;
    char* ot = ldsbuf + w * 8192;  // per-wave private 8KB; staging long done
#pragma unroll
    for (int m = 0; m < 4; ++m)
#pragma unroll
      for (int q = 0; q < 8; ++q) {
        u32 pk = cvtpk(oacc[m][2*q] * inv, oacc[m][2*q+1] * inv);
        int c2 = m * 64 + 4 * (q & 1) + 16 * (q >> 1) + 8 * h;  // byte col
        *(u32*)(ot + ln * 256 + (c2 ^ ((ln & 7) << 4))) = pk;
      }
    asm volatile("" ::: "memory");  // same-wave write->read ordering
    u16* orow = outT + ((size_t)bh * LSEQ + t0 + ln) * CHD;
#pragma unroll
    for (int it = 0; it < 8; ++it) {
      int col = h * 128 + it * 16;
      ushort8 d = *(const ushort8*)(ot + ln * 256 + (col ^ ((ln & 7) << 4)));
      *(ushort8*)((char*)orow + col) = d;
    }
  }
}

// ---- proj GEMM 512(o) x 8192(b*l) x 512(c): 128x128 tile, BK=64, counted-vmcnt dbuf ----
__global__ __launch_bounds__(256) void k_proj(const u16* __restrict__ Wm,    // bf16 [512][512]
                                              const u16* __restrict__ eT,    // bf16 [32][1024][128]
                                              const float* __restrict__ bias,
                                              u16* __restrict__ x,           // bf16 [8][512][1024]
                                              float* __restrict__ chsum,
                                              float* __restrict__ chsq) {
  __shared__ char lds[65536];  // A dbuf 2x16KB | B dbuf 2x16KB
  int lt = blockIdx.x, ot = blockIdx.y;
  int b = lt >> 3;
  int l0b = (lt & 7) * 128;
  int o0 = ot * 128;
  int tid = threadIdx.x, w = tid >> 6, lane = tid & 63, lo = lane & 15, hi = lane >> 4;
  int wm = w >> 1, wn = w & 1;
  const char* Wb = (const char*)Wm;
  const char* eTb = (const char*)eT;

  auto stageA = [&](int buf, int kb) {
    char* dst = lds + buf * 16384;
#pragma unroll
    for (int it = 0; it < 4; ++it) {
      int bb = it * 4096 + tid * 16;
      int row = bb >> 7;
      int cb = (bb & 127) ^ ((row & 7) << 4);
      gl_lds16(Wb + (size_t)(o0 + row) * 1024 + kb * 128 + cb, dst + bb);
    }
  };
  auto stageB = [&](int buf, int kb) {
    char* dst = lds + 32768 + buf * 16384;
    int page = b * 4 + (kb >> 1);
    int choff = (kb & 1) * 128;
#pragma unroll
    for (int it = 0; it < 4; ++it) {
      int bb = it * 4096 + tid * 16;
      int row = bb >> 7;
      int cb = (bb & 127) ^ ((row & 7) << 4);
      gl_lds16(eTb + ((size_t)page * 1024 + l0b + row) * 256 + choff + cb, dst + bb);
    }
  };

  floatx4 acc[4][4];
#pragma unroll
  for (int i = 0; i < 4; ++i)
#pragma unroll
    for (int j = 0; j < 4; ++j) { acc[i][j][0]=0.f; acc[i][j][1]=0.f; acc[i][j][2]=0.f; acc[i][j][3]=0.f; }

  stageA(0, 0); stageB(0, 0);

  for (int kb = 0; kb < 8; ++kb) {
    int cur = kb & 1;
    __builtin_amdgcn_s_barrier();                  // B1
    if (kb < 7) { stageA(cur ^ 1, kb + 1); stageB(cur ^ 1, kb + 1); }
    if (kb < 7) { asm volatile("s_waitcnt vmcnt(8)" ::: "memory"); }
    else        { asm volatile("s_waitcnt vmcnt(0)" ::: "memory"); }
    __builtin_amdgcn_s_barrier();                  // B2
    const char* A = lds + cur * 16384;
    const char* B = lds + 32768 + cur * 16384;
#pragma unroll
    for (int kk = 0; kk < 2; ++kk) {
      short8 af[4], bf[4];
#pragma unroll
      for (int mi = 0; mi < 4; ++mi) {
        int row = wm * 64 + mi * 16 + lo;
        af[mi] = *(const short8*)(A + row * 128 + ((kk * 64 + hi * 16) ^ ((row & 7) << 4)));
      }
#pragma unroll
      for (int ni = 0; ni < 4; ++ni) {
        int row = wn * 64 + ni * 16 + lo;
        bf[ni] = *(const short8*)(B + row * 128 + ((kk * 64 + hi * 16) ^ ((row & 7) << 4)));
      }
      __builtin_amdgcn_s_setprio(1);
#pragma unroll
      for (int mi = 0; mi < 4; ++mi)
#pragma unroll
        for (int ni = 0; ni < 4; ++ni)
          acc[mi][ni] = __builtin_amdgcn_mfma_f32_16x16x32_bf16(af[mi], bf[ni], acc[mi][ni], 0, 0, 0);
      __builtin_amdgcn_s_setprio(0);
    }
  }

  // epilogue: bias + x write (bf16) + per-channel partial stats (f32)
#pragma unroll
  for (int mi = 0; mi < 4; ++mi) {
#pragma unroll
    for (int r = 0; r < 4; ++r) {
      int o = o0 + wm * 64 + mi * 16 + hi * 4 + r;
      float bv = bias[o];
      float s = 0.f, q = 0.f;
#pragma unroll
      for (int ni = 0; ni < 4; ++ni) {
        float xv = acc[mi][ni][r] + bv;
        x[((size_t)b * 512 + o) * LSEQ + l0b + wn * 64 + ni * 16 + lo] = f2b(xv);
        s += xv; q += xv * xv;
      }
#pragma unroll
      for (int d = 1; d < 16; d <<= 1) { s += __shfl_xor(s, d); q += __shfl_xor(q, d); }
      if (lo == 0) {
        atomicAdd(&chsum[o], s);
        atomicAdd(&chsq[o], q);
      }
    }
  }
}

// ---- BN apply + swish (stats folded in): bf16 x in, f32 out ----
__global__ __launch_bounds__(256) void k_final(const u16* __restrict__ x,
                                               const float* __restrict__ chsum,
                                               const float* __restrict__ chsq,
                                               const float* __restrict__ gamma,
                                               const float* __restrict__ beta,
                                               float* __restrict__ out) {
  int idx = blockIdx.x * 256 + threadIdx.x;
  int base = idx * 8;
  int ch = (base >> 10) & 511;
  const float invn = 1.0f / 8192.0f;
  float mean = chsum[ch] * invn;
  float var = chsq[ch] * invn - mean * mean;
  float rstd = rsqrtf(var + 1e-5f);
  float sc = gamma[ch] * rstd;
  float sh = beta[ch] - mean * sc;
  ushort8 vx = *(const ushort8*)(x + base);
  f32x4 o0, o1;
#pragma unroll
  for (int j = 0; j < 8; ++j) {
    float xn = b2f(vx[j]) * sc + sh;
    float sg = 1.0f / (1.0f + __expf(-xn));
    float r = xn * sg;
    if (j < 4) o0[j] = r; else o1[j - 4] = r;
  }
  *(f32x4*)(out + base) = o0;
  *(f32x4*)(out + base + 4) = o1;
}

extern "C" void kernel_launch(void* const* d_in, const int* in_sizes, int n_in,
                              void* d_out, int out_size, void* d_ws, size_t ws_size,
                              hipStream_t stream) {
  const float* c     = (const float*)d_in[0];
  const float* e     = (const float*)d_in[1];
  const float* Wf    = (const float*)d_in[2];
  const float* bias  = (const float*)d_in[3];
  const float* gamma = (const float*)d_in[4];
  const float* beta  = (const float*)d_in[5];
  float* outp = (float*)d_out;

  char* ws = (char*)d_ws;
  const size_t TB = (size_t)32 * 1024 * 128 * 2;  // 8.39MB bf16 [bh][*][*] slot
  u16* eT  = (u16*)(ws);                 // S0
  u16* cT  = (u16*)(ws + TB);            // S1
  u16* cV  = (u16*)(ws + 2 * TB);        // S2
  u16* eV  = (u16*)(ws + 3 * TB);        // S3
  u16* xT  = (u16*)(ws + 4 * TB);        // S4: _eT (fused attn output)
  u16* Wbf = (u16*)(ws + 5 * TB);        // 512KB
  float* chsum = (float*)(ws + 5 * TB + (1 << 20));
  float* chsq  = chsum + 512;
  u16* x   = (u16*)(ws + 6 * TB);        // bf16 8.4MB

  dim3 tb(256);

  k_prep<<<dim3(16, 4, 66), tb, 0, stream>>>(c, e, Wf, cV, cT, eV, eT, Wbf, chsum);
  k_attn<<<dim3(32, 16), dim3(128), 0, stream>>>(eT, cT, cV, eV, xT);  // bh-major grid: bh%8 XCD map
  k_proj<<<dim3(64, 4), tb, 0, stream>>>(Wbf, xT, bias, x, chsum, chsq);
  k_final<<<dim3(2048), tb, 0, stream>>>(x, chsum, chsq, gamma, beta, outp);
}

// Round 11
// 106.226 us; speedup vs baseline: 1.2295x; 1.0584x over previous
//
#include <hip/hip_runtime.h>
#include <hip/hip_bf16.h>

typedef __attribute__((ext_vector_type(8))) short short8;
typedef __attribute__((ext_vector_type(4))) float floatx4;
typedef __attribute__((ext_vector_type(4))) float f32x4;
typedef __attribute__((ext_vector_type(16))) float f32x16;
typedef unsigned short u16;
typedef unsigned int u32;
typedef __attribute__((ext_vector_type(4))) unsigned int u32x4;
typedef __attribute__((ext_vector_type(8))) unsigned short ushort8;

#define LSEQ 1024
#define CHD  128
#define CEXP 0.12751744900425577f   // (1/sqrt(128)) * log2(e)
#define THR_RAW 62.73318f           // 8 / CEXP

static __device__ __forceinline__ float b2f(u16 u) {
  union { u32 i; float f; } x; x.i = ((u32)u) << 16; return x.f;
}
static __device__ __forceinline__ u16 f2b(float f) {
  __hip_bfloat16 h = __float2bfloat16(f);
  return *reinterpret_cast<u16*>(&h);
}
static __device__ __forceinline__ u32 cvtpk(float a, float b) {
  u32 r;
  asm("v_cvt_pk_bf16_f32 %0, %1, %2" : "=v"(r) : "v"(a), "v"(b));
  return r;
}
static __device__ __forceinline__ void swap32(u32& a, u32& b) {
  asm("v_permlane32_swap_b32 %0, %1" : "+v"(a), "+v"(b));
}
static __device__ __forceinline__ short8 mk8(u32 a, u32 b, u32 c, u32 d) {
  union { u32x4 u; short8 s; } x;
  x.u[0] = a; x.u[1] = b; x.u[2] = c; x.u[3] = d;
  return x.s;
}
static __device__ __forceinline__ float exp2f_fast(float x) {
  float r;
  asm("v_exp_f32 %0, %1" : "=v"(r) : "v"(x));
  return r;
}
static __device__ __forceinline__ void gl_lds16(const void* g, void* l) {
  __builtin_amdgcn_global_load_lds((__attribute__((address_space(1))) const void*)g,
                                   (__attribute__((address_space(3))) void*)l, 16, 0, 0);
}
#define BARRIER() do { asm volatile("" ::: "memory"); __builtin_amdgcn_s_barrier(); asm volatile("" ::: "memory"); } while (0)
#define LGKM0()   do { asm volatile("s_waitcnt lgkmcnt(0)" ::: "memory"); __builtin_amdgcn_sched_barrier(0); } while (0)

// ---- prep both inputs (z<64) + W convert (z=64,65) + stats zero ----
__global__ __launch_bounds__(256) void k_prep(const float* __restrict__ cin,
                                              const float* __restrict__ ein,
                                              const float* __restrict__ Wf,
                                              u16* __restrict__ cV, u16* __restrict__ cT,
                                              u16* __restrict__ eV, u16* __restrict__ eT,
                                              u16* __restrict__ wb, float* __restrict__ zbuf) {
  __shared__ u16 tile[32][72];
  int z = blockIdx.z;
  int tid = threadIdx.x;
  if (z >= 64) {
    int wblk = (z - 64) * 64 + blockIdx.y * 16 + blockIdx.x;
    int base = (wblk * 256 + tid) * 8;
    f32x4 a = *(const f32x4*)(Wf + base);
    f32x4 b = *(const f32x4*)(Wf + base + 4);
    u32x4 u;
    u[0] = cvtpk(a[0], a[1]); u[1] = cvtpk(a[2], a[3]);
    u[2] = cvtpk(b[0], b[1]); u[3] = cvtpk(b[2], b[3]);
    *(u32x4*)(wb + base) = u;
    if (wblk == 0) {
      f32x4 zz; zz[0]=0.f; zz[1]=0.f; zz[2]=0.f; zz[3]=0.f;
      *(f32x4*)(zbuf + tid * 4) = zz;
    }
    return;
  }
  const float* in = (z < 32) ? cin : ein;
  u16* outV = (z < 32) ? cV : eV;
  u16* outT = (z < 32) ? cT : eT;
  int bh = z & 31, c0 = blockIdx.y * 32, s0 = blockIdx.x * 64;
  int cl = tid >> 3, sc = tid & 7;
  size_t off = ((size_t)bh * CHD + c0 + cl) * LSEQ + s0 + sc * 8;
  f32x4 a = *(const f32x4*)(in + off);
  f32x4 b = *(const f32x4*)(in + off + 4);
  u32x4 u;
  u[0] = cvtpk(a[0], a[1]); u[1] = cvtpk(a[2], a[3]);
  u[2] = cvtpk(b[0], b[1]); u[3] = cvtpk(b[2], b[3]);
  *(u32x4*)(outV + off) = u;
  *(u32x4*)&tile[cl][sc * 8] = u;
  __syncthreads();
  int sl = tid >> 2, cc = tid & 3;
  ushort8 v;
#pragma unroll
  for (int j = 0; j < 8; ++j) v[j] = tile[cc * 8 + j][sl];
  *(ushort8*)(outT + ((size_t)bh * LSEQ + s0 + sl) * CHD + c0 + cc * 8) = v;
}

// ---- fused double flash attention: 4 waves (2 tw x 2 sw), phased schedule ----
// grid(32 bh, 16 tt), 256 thr. LDS 65.5KB -> 2 blocks/CU -> 2 waves/SIMD.
__global__ __launch_bounds__(256, 2) void k_attn(const u16* __restrict__ eT,
                                                 const u16* __restrict__ cT,
                                                 const u16* __restrict__ cV,
                                                 const u16* __restrict__ eV,
                                                 u16* __restrict__ outT) {
  __shared__ char ldsbuf[66560];  // K dbuf 2x16K @0 | V dbuf 2x16K @32768 | exch @65536

  int bh = blockIdx.x, tt = blockIdx.y;
  int tid = threadIdx.x;
  int w = tid >> 6, lane = tid & 63;
  int tw = w & 1, sw = w >> 1;
  int ln = lane & 31, h = lane >> 5;
  int t0 = tt * 64 + tw * 32;

  float* bmbuf = (float*)(ldsbuf + 65536);         // [tw*2+sw][32]
  float* lbuf  = (float*)(ldsbuf + 65536 + 512);   // [tw][32]

  auto stageK = [&](int buf, int sb, const char* kTb) {
#pragma unroll
    for (int it = 0; it < 4; ++it) {
      int bb = it * 4096 + tid * 16;
      int row = bb >> 8;
      int cb = (bb & 255) ^ ((row & 15) << 4);
      gl_lds16(kTb + (size_t)(sb * 64 + row) * 256 + cb, ldsbuf + buf * 16384 + bb);
    }
  };
  auto stageV = [&](int buf, int sb, const char* vb) {
#pragma unroll
    for (int it = 0; it < 4; ++it) {
      int bb = it * 4096 + tid * 16;
      int row = bb >> 7;
      int cb = (bb & 127) ^ ((row & 7) << 4);
      gl_lds16(vb + (size_t)row * 2048 + sb * 128 + cb, ldsbuf + 32768 + buf * 16384 + bb);
    }
  };

  short8 bq[8];
  f32x16 oacc[4];
  float m_r, l_r;
  int swz = (ln & 7) << 4;     // V-row & Q-tile swizzle
  int kswz = (ln & 15) << 4;   // K-row swizzle (krow&15 == ln&15)
  int krow = sw * 32 + ln;

  auto flash = [&](const char* kTb, const char* vb) {
    m_r = -1e30f; l_r = 0.f;
#pragma unroll
    for (int i = 0; i < 4; ++i)
#pragma unroll
      for (int r = 0; r < 16; ++r) oacc[i][r] = 0.f;

    stageK(0, 0, kTb); stageV(0, 0, vb);
    asm volatile("s_waitcnt vmcnt(0)" ::: "memory");
    BARRIER();

    for (int sb = 0; sb < 16; ++sb) {
      int cur = sb & 1;
      const char* K = ldsbuf + cur * 16384;
      const char* V = ldsbuf + 32768 + cur * 16384;
      f32x16 sa;
#pragma unroll
      for (int r = 0; r < 16; ++r) sa[r] = 0.f;

      // ---- P1: QK k=0..3 ----
      if (sb < 15) stageK(cur ^ 1, sb + 1, kTb);
      short8 ka0 = *(const short8*)(K + krow * 256 + ((0  + h * 16) ^ kswz));
      short8 ka1 = *(const short8*)(K + krow * 256 + ((32 + h * 16) ^ kswz));
      short8 ka2 = *(const short8*)(K + krow * 256 + ((64 + h * 16) ^ kswz));
      short8 ka3 = *(const short8*)(K + krow * 256 + ((96 + h * 16) ^ kswz));
      BARRIER();
      LGKM0();
      __builtin_amdgcn_s_setprio(1);
      sa = __builtin_amdgcn_mfma_f32_32x32x16_bf16(ka0, bq[0], sa, 0, 0, 0);
      sa = __builtin_amdgcn_mfma_f32_32x32x16_bf16(ka1, bq[1], sa, 0, 0, 0);
      sa = __builtin_amdgcn_mfma_f32_32x32x16_bf16(ka2, bq[2], sa, 0, 0, 0);
      sa = __builtin_amdgcn_mfma_f32_32x32x16_bf16(ka3, bq[3], sa, 0, 0, 0);
      __builtin_amdgcn_s_setprio(0);
      BARRIER();

      // ---- P2: QK k=4..7 ----
      if (sb < 15) stageV(cur ^ 1, sb + 1, vb);
      short8 kb0 = *(const short8*)(K + krow * 256 + ((128 + h * 16) ^ kswz));
      short8 kb1 = *(const short8*)(K + krow * 256 + ((160 + h * 16) ^ kswz));
      short8 kb2 = *(const short8*)(K + krow * 256 + ((192 + h * 16) ^ kswz));
      short8 kb3 = *(const short8*)(K + krow * 256 + ((224 + h * 16) ^ kswz));
      BARRIER();
      LGKM0();
      __builtin_amdgcn_s_setprio(1);
      sa = __builtin_amdgcn_mfma_f32_32x32x16_bf16(kb0, bq[4], sa, 0, 0, 0);
      sa = __builtin_amdgcn_mfma_f32_32x32x16_bf16(kb1, bq[5], sa, 0, 0, 0);
      sa = __builtin_amdgcn_mfma_f32_32x32x16_bf16(kb2, bq[6], sa, 0, 0, 0);
      sa = __builtin_amdgcn_mfma_f32_32x32x16_bf16(kb3, bq[7], sa, 0, 0, 0);
      __builtin_amdgcn_s_setprio(0);
      BARRIER();

      // ---- P3: joint softmax (VALU phase; partner blocks' MFMAs fill the SIMD) ----
      float bm = fmaxf(fmaxf(sa[0], sa[1]), fmaxf(sa[2], sa[3]));
      bm = fmaxf(bm, fmaxf(fmaxf(sa[4], sa[5]), fmaxf(sa[6], sa[7])));
      bm = fmaxf(bm, fmaxf(fmaxf(sa[8], sa[9]), fmaxf(sa[10], sa[11])));
      bm = fmaxf(bm, fmaxf(fmaxf(sa[12], sa[13]), fmaxf(sa[14], sa[15])));
      bm = fmaxf(bm, __shfl_xor(bm, 32));
      if (lane < 32) bmbuf[(tw * 2 + sw) * 32 + lane] = bm;
      LGKM0();
      BARRIER();
      bm = fmaxf(bm, bmbuf[(tw * 2 + (sw ^ 1)) * 32 + ln]);  // joint max over 64 s
      bool stay = __all(bm - m_r <= THR_RAW);
      if (!stay) {
        float mn = fmaxf(m_r, bm);
        float corr = exp2f_fast((m_r - mn) * CEXP);
        m_r = mn; l_r *= corr;
#pragma unroll
        for (int i = 0; i < 4; ++i)
#pragma unroll
          for (int r = 0; r < 16; ++r) oacc[i][r] *= corr;
      }
      float mnC = m_r * CEXP;
      float rs = 0.f;
#pragma unroll
      for (int r = 0; r < 16; ++r) {
        float p = exp2f_fast(__builtin_fmaf(sa[r], CEXP, -mnC));
        sa[r] = p; rs += p;
      }
      rs += __shfl_xor(rs, 32);
      l_r += rs;  // partial l over this wave's s-half

      short8 bp0, bp1;
      {
        u32 w0 = cvtpk(sa[0], sa[1]),  w1 = cvtpk(sa[2], sa[3]);
        u32 w2 = cvtpk(sa[4], sa[5]),  w3 = cvtpk(sa[6], sa[7]);
        swap32(w0, w2); swap32(w1, w3);
        bp0 = mk8(w0, w1, w2, w3);
        u32 w4 = cvtpk(sa[8], sa[9]),  w5 = cvtpk(sa[10], sa[11]);
        u32 w6 = cvtpk(sa[12], sa[13]), w7 = cvtpk(sa[14], sa[15]);
        swap32(w4, w6); swap32(w5, w7);
        bp1 = mk8(w4, w5, w6, w7);
      }

      // ---- P4: PV ks=0 (k = sw*32 + 0..15) ----
      int vc0 = sw * 64 + h * 16;
      short8 va0 = *(const short8*)(V + (0  + ln) * 128 + (vc0 ^ swz));
      short8 va1 = *(const short8*)(V + (32 + ln) * 128 + (vc0 ^ swz));
      short8 va2 = *(const short8*)(V + (64 + ln) * 128 + (vc0 ^ swz));
      short8 va3 = *(const short8*)(V + (96 + ln) * 128 + (vc0 ^ swz));
      BARRIER();
      LGKM0();
      __builtin_amdgcn_s_setprio(1);
      oacc[0] = __builtin_amdgcn_mfma_f32_32x32x16_bf16(va0, bp0, oacc[0], 0, 0, 0);
      oacc[1] = __builtin_amdgcn_mfma_f32_32x32x16_bf16(va1, bp0, oacc[1], 0, 0, 0);
      oacc[2] = __builtin_amdgcn_mfma_f32_32x32x16_bf16(va2, bp0, oacc[2], 0, 0, 0);
      oacc[3] = __builtin_amdgcn_mfma_f32_32x32x16_bf16(va3, bp0, oacc[3], 0, 0, 0);
      __builtin_amdgcn_s_setprio(0);
      BARRIER();

      // ---- P5: PV ks=1 (k = sw*32 + 16..31) ----
      int vc1 = sw * 64 + 32 + h * 16;
      short8 vb0 = *(const short8*)(V + (0  + ln) * 128 + (vc1 ^ swz));
      short8 vb1 = *(const short8*)(V + (32 + ln) * 128 + (vc1 ^ swz));
      short8 vb2 = *(const short8*)(V + (64 + ln) * 128 + (vc1 ^ swz));
      short8 vb3 = *(const short8*)(V + (96 + ln) * 128 + (vc1 ^ swz));
      BARRIER();
      LGKM0();
      __builtin_amdgcn_s_setprio(1);
      oacc[0] = __builtin_amdgcn_mfma_f32_32x32x16_bf16(vb0, bp1, oacc[0], 0, 0, 0);
      oacc[1] = __builtin_amdgcn_mfma_f32_32x32x16_bf16(vb1, bp1, oacc[1], 0, 0, 0);
      oacc[2] = __builtin_amdgcn_mfma_f32_32x32x16_bf16(vb2, bp1, oacc[2], 0, 0, 0);
      oacc[3] = __builtin_amdgcn_mfma_f32_32x32x16_bf16(vb3, bp1, oacc[3], 0, 0, 0);
      __builtin_amdgcn_s_setprio(0);
      // end-of-iter: confirm stage(sb+1) landed everywhere (issued ~4 phases ago)
      asm volatile("s_waitcnt vmcnt(0)" ::: "memory");
      BARRIER();
    }
  };

  auto merge_sw = [&]() {  // O_total = O(sw0)+O(sw1); l_total; result lands in sw0
    float* mb = (float*)(ldsbuf + 32768 + tw * 16384);
    if (sw == 1) {
#pragma unroll
      for (int i = 0; i < 4; ++i)
#pragma unroll
        for (int r = 0; r < 16; ++r) mb[(i * 16 + r) * 64 + lane] = oacc[i][r];
      if (lane < 32) lbuf[tw * 32 + lane] = l_r;
    }
    LGKM0();
    BARRIER();
    if (sw == 0) {
#pragma unroll
      for (int i = 0; i < 4; ++i)
#pragma unroll
        for (int r = 0; r < 16; ++r) oacc[i][r] += mb[(i * 16 + r) * 64 + lane];
      l_r += lbuf[tw * 32 + ln];
    }
  };

  // ---------------- phase 1: _c tile = attn(e, c, c) ----------------
  const u16* qbase = eT + ((size_t)bh * LSEQ + t0 + ln) * CHD + h * 8;
#pragma unroll
  for (int k = 0; k < 8; ++k) bq[k] = *(const short8*)(qbase + k * 16);

  flash((const char*)(cT + (size_t)bh * LSEQ * CHD),
        (const char*)(cV + (size_t)bh * CHD * LSEQ));

  merge_sw();
  // sw0 writes normalized bf16 Q tile [32 t][256B c] (swizzled) for all waves
  if (sw == 0) {
    float inv = 1.0f / l_r;
    char* qt = ldsbuf + tw * 8192;
#pragma unroll
    for (int m = 0; m < 4; ++m)
#pragma unroll
      for (int q = 0; q < 8; ++q) {
        u32 pk = cvtpk(oacc[m][2 * q] * inv, oacc[m][2 * q + 1] * inv);
        int c2 = m * 64 + 4 * (q & 1) + 16 * (q >> 1) + 8 * h;
        *(u32*)(qt + ln * 256 + (c2 ^ swz)) = pk;
      }
  }
  LGKM0();
  BARRIER();
  {
    const char* qt = ldsbuf + tw * 8192;
#pragma unroll
    for (int k = 0; k < 8; ++k)
      bq[k] = *(const short8*)(qt + ln * 256 + ((k * 32 + h * 16) ^ swz));
  }
  LGKM0();
  BARRIER();  // all bq reads done before phase-2 staging overwrites K area

  // ---------------- phase 2: _e tile = attn(_c, e, e) ----------------
  flash((const char*)(eT + (size_t)bh * LSEQ * CHD),
        (const char*)(eV + (size_t)bh * CHD * LSEQ));

  merge_sw();
  BARRIER();
  if (sw == 0) {
    float inv = 1.0f / l_r;
    char* ot = ldsbuf + tw * 8192;
#pragma unroll
    for (int m = 0; m < 4; ++m)
#pragma unroll
      for (int q = 0; q < 8; ++q) {
        u32 pk = cvtpk(oacc[m][2 * q] * inv, oacc[m][2 * q + 1] * inv);
        int c2 = m * 64 + 4 * (q & 1) + 16 * (q >> 1) + 8 * h;
        *(u32*)(ot + ln * 256 + (c2 ^ swz)) = pk;
      }
    asm volatile("" ::: "memory");
    u16* orow = outT + ((size_t)bh * LSEQ + t0 + ln) * CHD;
#pragma unroll
    for (int it = 0; it < 8; ++it) {
      int col = h * 128 + it * 16;
      ushort8 d = *(const ushort8*)(ot + ln * 256 + (col ^ swz));
      *(ushort8*)((char*)orow + col) = d;
    }
  }
}

// ---- proj GEMM 512(o) x 8192(b*l) x 512(c): 128x128 tile, BK=64, counted-vmcnt dbuf ----
__global__ __launch_bounds__(256) void k_proj(const u16* __restrict__ Wm,
                                              const u16* __restrict__ eT,
                                              const float* __restrict__ bias,
                                              u16* __restrict__ x,
                                              float* __restrict__ chsum,
                                              float* __restrict__ chsq) {
  __shared__ char lds[65536];
  int lt = blockIdx.x, ot = blockIdx.y;
  int b = lt >> 3;
  int l0b = (lt & 7) * 128;
  int o0 = ot * 128;
  int tid = threadIdx.x, w = tid >> 6, lane = tid & 63, lo = lane & 15, hi = lane >> 4;
  int wm = w >> 1, wn = w & 1;
  const char* Wb = (const char*)Wm;
  const char* eTb = (const char*)eT;

  auto stageA = [&](int buf, int kb) {
    char* dst = lds + buf * 16384;
#pragma unroll
    for (int it = 0; it < 4; ++it) {
      int bb = it * 4096 + tid * 16;
      int row = bb >> 7;
      int cb = (bb & 127) ^ ((row & 7) << 4);
      gl_lds16(Wb + (size_t)(o0 + row) * 1024 + kb * 128 + cb, dst + bb);
    }
  };
  auto stageB = [&](int buf, int kb) {
    char* dst = lds + 32768 + buf * 16384;
    int page = b * 4 + (kb >> 1);
    int choff = (kb & 1) * 128;
#pragma unroll
    for (int it = 0; it < 4; ++it) {
      int bb = it * 4096 + tid * 16;
      int row = bb >> 7;
      int cb = (bb & 127) ^ ((row & 7) << 4);
      gl_lds16(eTb + ((size_t)page * 1024 + l0b + row) * 256 + choff + cb, dst + bb);
    }
  };

  floatx4 acc[4][4];
#pragma unroll
  for (int i = 0; i < 4; ++i)
#pragma unroll
    for (int j = 0; j < 4; ++j) { acc[i][j][0]=0.f; acc[i][j][1]=0.f; acc[i][j][2]=0.f; acc[i][j][3]=0.f; }

  stageA(0, 0); stageB(0, 0);

  for (int kb = 0; kb < 8; ++kb) {
    int cur = kb & 1;
    __builtin_amdgcn_s_barrier();
    if (kb < 7) { stageA(cur ^ 1, kb + 1); stageB(cur ^ 1, kb + 1); }
    if (kb < 7) { asm volatile("s_waitcnt vmcnt(8)" ::: "memory"); }
    else        { asm volatile("s_waitcnt vmcnt(0)" ::: "memory"); }
    __builtin_amdgcn_s_barrier();
    const char* A = lds + cur * 16384;
    const char* B = lds + 32768 + cur * 16384;
#pragma unroll
    for (int kk = 0; kk < 2; ++kk) {
      short8 af[4], bf[4];
#pragma unroll
      for (int mi = 0; mi < 4; ++mi) {
        int row = wm * 64 + mi * 16 + lo;
        af[mi] = *(const short8*)(A + row * 128 + ((kk * 64 + hi * 16) ^ ((row & 7) << 4)));
      }
#pragma unroll
      for (int ni = 0; ni < 4; ++ni) {
        int row = wn * 64 + ni * 16 + lo;
        bf[ni] = *(const short8*)(B + row * 128 + ((kk * 64 + hi * 16) ^ ((row & 7) << 4)));
      }
      __builtin_amdgcn_s_setprio(1);
#pragma unroll
      for (int mi = 0; mi < 4; ++mi)
#pragma unroll
        for (int ni = 0; ni < 4; ++ni)
          acc[mi][ni] = __builtin_amdgcn_mfma_f32_16x16x32_bf16(af[mi], bf[ni], acc[mi][ni], 0, 0, 0);
      __builtin_amdgcn_s_setprio(0);
    }
  }

#pragma unroll
  for (int mi = 0; mi < 4; ++mi) {
#pragma unroll
    for (int r = 0; r < 4; ++r) {
      int o = o0 + wm * 64 + mi * 16 + hi * 4 + r;
      float bv = bias[o];
      float s = 0.f, q = 0.f;
#pragma unroll
      for (int ni = 0; ni < 4; ++ni) {
        float xv = acc[mi][ni][r] + bv;
        x[((size_t)b * 512 + o) * LSEQ + l0b + wn * 64 + ni * 16 + lo] = f2b(xv);
        s += xv; q += xv * xv;
      }
#pragma unroll
      for (int d = 1; d < 16; d <<= 1) { s += __shfl_xor(s, d); q += __shfl_xor(q, d); }
      if (lo == 0) {
        atomicAdd(&chsum[o], s);
        atomicAdd(&chsq[o], q);
      }
    }
  }
}

// ---- BN apply + swish (stats folded in): bf16 x in, f32 out ----
__global__ __launch_bounds__(256) void k_final(const u16* __restrict__ x,
                                               const float* __restrict__ chsum,
                                               const float* __restrict__ chsq,
                                               const float* __restrict__ gamma,
                                               const float* __restrict__ beta,
                                               float* __restrict__ out) {
  int idx = blockIdx.x * 256 + threadIdx.x;
  int base = idx * 8;
  int ch = (base >> 10) & 511;
  const float invn = 1.0f / 8192.0f;
  float mean = chsum[ch] * invn;
  float var = chsq[ch] * invn - mean * mean;
  float rstd = rsqrtf(var + 1e-5f);
  float sc = gamma[ch] * rstd;
  float sh = beta[ch] - mean * sc;
  ushort8 vx = *(const ushort8*)(x + base);
  f32x4 o0, o1;
#pragma unroll
  for (int j = 0; j < 8; ++j) {
    float xn = b2f(vx[j]) * sc + sh;
    float sg = 1.0f / (1.0f + __expf(-xn));
    float r = xn * sg;
    if (j < 4) o0[j] = r; else o1[j - 4] = r;
  }
  *(f32x4*)(out + base) = o0;
  *(f32x4*)(out + base + 4) = o1;
}

extern "C" void kernel_launch(void* const* d_in, const int* in_sizes, int n_in,
                              void* d_out, int out_size, void* d_ws, size_t ws_size,
                              hipStream_t stream) {
  const float* c     = (const float*)d_in[0];
  const float* e     = (const float*)d_in[1];
  const float* Wf    = (const float*)d_in[2];
  const float* bias  = (const float*)d_in[3];
  const float* gamma = (const float*)d_in[4];
  const float* beta  = (const float*)d_in[5];
  float* outp = (float*)d_out;

  char* ws = (char*)d_ws;
  const size_t TB = (size_t)32 * 1024 * 128 * 2;
  u16* eT  = (u16*)(ws);
  u16* cT  = (u16*)(ws + TB);
  u16* cV  = (u16*)(ws + 2 * TB);
  u16* eV  = (u16*)(ws + 3 * TB);
  u16* xT  = (u16*)(ws + 4 * TB);
  u16* Wbf = (u16*)(ws + 5 * TB);
  float* chsum = (float*)(ws + 5 * TB + (1 << 20));
  float* chsq  = chsum + 512;
  u16* x   = (u16*)(ws + 6 * TB);

  dim3 tb(256);

  k_prep<<<dim3(16, 4, 66), tb, 0, stream>>>(c, e, Wf, cV, cT, eV, eT, Wbf, chsum);
  k_attn<<<dim3(32, 16), tb, 0, stream>>>(eT, cT, cV, eV, xT);
  k_proj<<<dim3(64, 4), tb, 0, stream>>>(Wbf, xT, bias, x, chsum, chsq);
  k_final<<<dim3(2048), tb, 0, stream>>>(x, chsum, chsq, gamma, beta, outp);
}